// Round 14
// baseline (3345.733 us; speedup 1.0000x reference)
//
#include <hip/hip_runtime.h>
#include <math.h>

#define N 1024
#define NN (1024*1024)
#define BATCH 8

static constexpr float MU1 = 1e-6f, MU2 = 1e-5f, MU3 = 1e-5f;

__device__ __forceinline__ float2 cmulf(float2 a, float2 b){
  return make_float2(a.x*b.x - a.y*b.y, a.x*b.y + a.y*b.x);
}
__device__ __forceinline__ float2 conjf(float2 a){ return make_float2(a.x, -a.y); }
__device__ __forceinline__ float softf(float v, float T){
  float a = fmaxf(fabsf(v) - T, 0.f);
  return copysignf(a, v);
}
__device__ __forceinline__ int rev4_10(int p){
  return ((p&3)<<8) | (((p>>2)&3)<<6) | (((p>>4)&3)<<4) | (((p>>6)&3)<<2) | ((p>>8)&3);
}
__device__ __forceinline__ int foldc(int k){
  if (k == 0) return 0;
  if (k == 512) return 1;
  return (k < 512) ? 2*k : 2*(1024-k)+1;
}
__device__ __forceinline__ int unfoldc(int c){
  if (c < 2) return c ? 512 : 0;
  return (c & 1) ? 1024 - ((c-1)>>1) : (c>>1);
}
__device__ __forceinline__ float2* ZP(float2* Zw, float2* Zd, int ce){
  return (ce == 7) ? Zd : (Zw + (size_t)ce * NN);
}

#define BF4F(x0,x1,x2,x3,u0,u1,u2,u3) { \
  float2 t02p = make_float2((x0).x+(x2).x, (x0).y+(x2).y); \
  float2 t02m = make_float2((x0).x-(x2).x, (x0).y-(x2).y); \
  float2 t13p = make_float2((x1).x+(x3).x, (x1).y+(x3).y); \
  float2 t13m = make_float2((x1).x-(x3).x, (x1).y-(x3).y); \
  u0 = make_float2(t02p.x+t13p.x, t02p.y+t13p.y); \
  u2 = make_float2(t02p.x-t13p.x, t02p.y-t13p.y); \
  u1 = make_float2(t02m.x+t13m.y, t02m.y-t13m.x); \
  u3 = make_float2(t02m.x-t13m.y, t02m.y+t13m.x); }
#define BF4I(x0,x1,x2,x3,u0,u1,u2,u3) { \
  float2 t02p = make_float2((x0).x+(x2).x, (x0).y+(x2).y); \
  float2 t02m = make_float2((x0).x-(x2).x, (x0).y-(x2).y); \
  float2 t13p = make_float2((x1).x+(x3).x, (x1).y+(x3).y); \
  float2 t13m = make_float2((x1).x-(x3).x, (x1).y-(x3).y); \
  u0 = make_float2(t02p.x+t13p.x, t02p.y+t13p.y); \
  u2 = make_float2(t02p.x-t13p.x, t02p.y-t13p.y); \
  u1 = make_float2(t02m.x-t13m.y, t02m.y+t13m.x); \
  u3 = make_float2(t02m.x+t13m.y, t02m.y-t13m.x); }

// generate Ws[0..cnt) = exp(-2*pi*i*j/1024) in LDS
__device__ __forceinline__ void genWs(float2* Ws, int cnt, int tid, int nthr){
  for (int j = tid; j < cnt; j += nthr){
    double a = (double)j * (-M_PI / 512.0);
    float s, c;
    sincosf((float)a, &s, &c);
    Ws[j] = make_float2(c, s);
  }
}

// ---------------- 1024-pt Stockham radix-2 FFT (precompute row passes) ------
template<int DIR>
__device__ __forceinline__ void fft1024(float2* bufA, float2* bufB,
                                        const float2* Ws, int tid){
  float2* cur = bufA; float2* oth = bufB;
  int s = 1;
  for (int st = 0; st < 10; ++st){
    int m = 512 >> st;
    #pragma unroll
    for (int bb = 0; bb < 2; ++bb){
      int b = tid + bb*256;
      int p = b >> st;
      int q = b & (s-1);
      float2 a = cur[b];
      float2 c = cur[b + 512];
      float2 w = Ws[b & ~(s-1)];
      if (DIR > 0) w.y = -w.y;
      float2 d = make_float2(a.x - c.x, a.y - c.y);
      oth[q + s*(2*p)]   = make_float2(a.x + c.x, a.y + c.y);
      oth[q + s*(2*p+1)] = cmulf(d, w);
    }
    __syncthreads();
    float2* t = cur; cur = oth; oth = t;
    s <<= 1;
  }
}

// ======== in-place single-row radix-4 FFT, 256 threads, 5 syncs =============
#define A1(p) ((p) + ((p)>>4))    // padded addr, uniform 4/bank-pair per stage

__device__ __forceinline__ void fwd_r4_row(float2* t4, const float2* Ws, int tid){
  #pragma unroll
  for (int s = 0; s < 5; ++s){
    int log2L = 8 - 2*s;
    int L = 1 << log2L;
    int j = tid & (L-1);
    int base = ((tid >> log2L) << (log2L+2)) + j;
    int tw = j << (2*s);
    float2 x0 = t4[A1(base)],     x1 = t4[A1(base+L)],
           x2 = t4[A1(base+2*L)], x3 = t4[A1(base+3*L)];
    float2 u0,u1,u2,u3;
    BF4F(x0,x1,x2,x3,u0,u1,u2,u3);
    t4[A1(base)]     = u0;
    t4[A1(base+L)]   = cmulf(u1, Ws[tw]);
    t4[A1(base+2*L)] = cmulf(u2, Ws[2*tw]);
    t4[A1(base+3*L)] = cmulf(u3, Ws[3*tw]);
    __syncthreads();
  }
}

__device__ __forceinline__ void inv_r4_row(float2* t4, const float2* Ws, int tid){
  #pragma unroll
  for (int s = 0; s < 5; ++s){
    int H = 1 << (2*s);
    int j = tid & (H-1);
    int base = ((tid >> (2*s)) << (2*s+2)) + j;
    int tw = j << (8 - 2*s);
    float2 x0 = t4[A1(base)];
    float2 x1 = cmulf(t4[A1(base+H)],   conjf(Ws[tw]));
    float2 x2 = cmulf(t4[A1(base+2*H)], conjf(Ws[2*tw]));
    float2 x3 = cmulf(t4[A1(base+3*H)], conjf(Ws[3*tw]));
    float2 u0,u1,u2,u3;
    BF4I(x0,x1,x2,x3,u0,u1,u2,u3);
    t4[A1(base)] = u0;     t4[A1(base+H)] = u1;
    t4[A1(base+2*H)] = u2; t4[A1(base+3*H)] = u3;
    __syncthreads();
  }
}

// ---------------- precompute ----------------
__global__ void k_build_h(const float* __restrict__ h, float2* __restrict__ Z){
  int idx = blockIdx.x*256 + threadIdx.x; // NN
  int i = idx >> 10, j = idx & 1023;
  float v = 0.f;
  if (i >= 256 && i < 768 && j >= 256 && j < 768)
    v = h[(i-256)*512 + (j-256)];
  Z[idx] = make_float2(v, 0.f);
}

template<int DIR>
__global__ __launch_bounds__(256) void k_fft_row(float2* Z){
  __shared__ float2 bufA[N], bufB[N], Ws[512];
  int tid = threadIdx.x;
  size_t base = ((size_t)blockIdx.y * N + blockIdx.x) * N;
  genWs(Ws, 512, tid, 256);
  for (int k = tid; k < N; k += 256) bufA[k] = Z[base + k];
  __syncthreads();
  fft1024<DIR>(bufA, bufB, Ws, tid);
  for (int k = tid; k < N; k += 256) Z[base + k] = bufA[k];
}

__global__ void k_transpose_ip(float2* Z){
  __shared__ float2 ta[32][33], tb[32][33];
  int t = blockIdx.x, ti = 0;
  while (t >= 32 - ti){ t -= 32 - ti; ti++; }
  int tj = ti + t;
  size_t base = (size_t)blockIdx.y * NN;
  int ra = ti*32, ca = tj*32;
  for (int k = threadIdx.y; k < 32; k += 8){
    ta[k][threadIdx.x] = Z[base + (size_t)(ra+k)*N + ca + threadIdx.x];
    if (ti != tj)
      tb[k][threadIdx.x] = Z[base + (size_t)(ca+k)*N + ra + threadIdx.x];
  }
  __syncthreads();
  for (int k = threadIdx.y; k < 32; k += 8){
    Z[base + (size_t)(ra+k)*N + ca + threadIdx.x] = (ti!=tj) ? tb[threadIdx.x][k]
                                                             : ta[threadIdx.x][k];
    if (ti != tj)
      Z[base + (size_t)(ca+k)*N + ra + threadIdx.x] = ta[threadIdx.x][k];
  }
}

// ZT[idx] = fft2(pad h) at (k_j = idx>>10, k_i = idx&1023).
// Blocked 8-col colpass layout: HfCb[blk][p][c], k_i=rev4(p), k_j=unfold(blk*8+c).
__global__ void k_filters2(const float2* __restrict__ ZT, float2* __restrict__ HfCb){
  int id = blockIdx.x*256 + threadIdx.x; // NN
  int blk = id >> 13;
  int rem = id & 8191;
  int p = rem >> 3, c = rem & 7;
  int colp = (blk << 3) | c;
  int ki = rev4_10(p);
  int kj = unfoldc(colp);
  float2 v = ZT[((size_t)kj << 10) | (size_t)ki];
  float sgn = ((ki + kj) & 1) ? -1.f : 1.f;
  HfCb[id] = make_float2(sgn*v.x, sgn*v.y);
}

// ---------------- pA: fused G0-update + s-build + radix-4 fwd row FFT --------
// mode 0: normal. mode 1 (t==1): G0r treated as zero. mode 2 (t==0): all state
// zero, z = i*M0(y), no state reads/writes.
__global__ __launch_bounds__(256) void k_pA(const float* __restrict__ X,
                                            const float* __restrict__ G0r,
                                            float* __restrict__ G0w,
                                            const float* __restrict__ G1,
                                            const float* __restrict__ K,
                                            const float* __restrict__ M,
                                            const float* __restrict__ y,
                                            float2* __restrict__ Zw,
                                            float2* __restrict__ Zd,
                                            int e0, int mode){
  __shared__ float2 t4[1088], Ws[768];
  int tid = threadIdx.x;
  int bid = blockIdx.x;
  int i = ((bid & 7) << 7) + (bid >> 3);   // XCD row-chunk swizzle
  int ce = blockIdx.y, e = e0 + ce;
  size_t eb  = (size_t)e*NN;
  size_t rb  = eb + (size_t)i*N;
  size_t rbm = eb + (size_t)((i-1)&1023)*N;
  size_t rbp = eb + (size_t)((i+1)&1023)*N;
  float2* Zp = ZP(Zw, Zd, ce);
  size_t zb  = (size_t)i*N;
  genWs(Ws, 768, tid, 256);
  const float T = 1e4f;                    // TAU/MU2
  if (mode == 2){
    bool rcent = (i >= 256 && i < 768);
    for (int j = tid; j < N; j += 256){
      float m0 = 0.f;
      if (rcent && j >= 256 && j < 768)
        m0 = y[(size_t)e*262144 + (size_t)(i-256)*512 + (j-256)] * (MU1/(1.f + MU1));
      t4[A1(j)] = make_float2(0.f, m0);
    }
  } else {
    for (int j = tid; j < N; j += 256){
      float xm = X[rbm+j], x = X[rb+j], xp = X[rbp+j];
      float psi0  = xm - x;
      float psi0p = x - xp;                // psi0 at row i+1
      float g0  = (mode == 1) ? 0.f : G0r[rb+j];
      float g0p = (mode == 1) ? 0.f : G0r[rbp+j];
      float u0  = softf(2.f*psi0  - g0 *(1.f/MU2), T);
      float u0p = softf(2.f*psi0p - g0p*(1.f/MU2), T);
      float g0n  = MU2*(u0  - psi0 ) + g0;
      float g0np = MU2*(u0p - psi0p) + g0p;
      G0w[rb+j] = g0n;
      int jp = (j+1) & 1023;
      float s = K[rb+j] + (g0np - g0n) + (G1[rb+jp] - G1[rb+j]);
      t4[A1(j)] = make_float2(s, M[rb+j]);
    }
  }
  __syncthreads();
  fwd_r4_row(t4, Ws, tid);
  // storage order: Z[c] = F(unfoldc(c)); DIF left F(k) at pos rev4(k)
  for (int c = tid; c < N; c += 256)
    Zp[zb + c] = t4[A1(rev4_10(unfoldc(c)))];
}

// ---------------- fused column pass: radix-4 (2 stages/sync) + combine -------
#define TADDR(r,c) ((((r)*9) + (c)) ^ (((r) & 16) >> 1))
#define CPV 512
__global__ __launch_bounds__(CPV) void k_colpass(float2* __restrict__ Zw,
    float2* __restrict__ Zd, const float2* __restrict__ HfCb){
  __shared__ float2 tile[9216];
  __shared__ float2 Ws[768];
  int tid = threadIdx.x;
  int blk = blockIdx.x;              // 128 col-groups of 8
  float2* Zp = ZP(Zw, Zd, blockIdx.y);
  size_t zbase = (size_t)(blk<<3);
  genWs(Ws, 768, tid, CPV);
  for (int k = tid; k < 8192; k += CPV){
    int r = k >> 3, c = k & 7;
    tile[TADDR(r,c)] = Zp[zbase + (size_t)r*N + c];
  }
  __syncthreads();
  // forward stages 0+1
  {
    int c = tid & 7, j2 = tid >> 3;
    float2 v[4][4];
    #pragma unroll
    for (int a = 0; a < 4; ++a)
      #pragma unroll
      for (int b = 0; b < 4; ++b)
        v[a][b] = tile[TADDR(j2 + 64*b + 256*a, c)];
    #pragma unroll
    for (int b = 0; b < 4; ++b){
      int j1 = j2 + 64*b;
      float2 u0,u1,u2,u3;
      BF4F(v[0][b],v[1][b],v[2][b],v[3][b],u0,u1,u2,u3);
      v[0][b] = u0;
      v[1][b] = cmulf(u1, Ws[j1]);
      v[2][b] = cmulf(u2, Ws[2*j1]);
      v[3][b] = cmulf(u3, Ws[3*j1]);
    }
    int tw = j2 << 2;
    #pragma unroll
    for (int a = 0; a < 4; ++a){
      float2 u0,u1,u2,u3;
      BF4F(v[a][0],v[a][1],v[a][2],v[a][3],u0,u1,u2,u3);
      tile[TADDR(j2 + 256*a, c)]       = u0;
      tile[TADDR(j2 + 64 + 256*a, c)]  = cmulf(u1, Ws[tw]);
      tile[TADDR(j2 + 128 + 256*a, c)] = cmulf(u2, Ws[2*tw]);
      tile[TADDR(j2 + 192 + 256*a, c)] = cmulf(u3, Ws[3*tw]);
    }
  }
  __syncthreads();
  // forward stages 2+3
  {
    int c = tid & 7, vv = tid >> 3;
    int B2 = vv >> 2, j2 = vv & 3;
    int r0 = 64*B2 + j2;
    float2 v[4][4];
    #pragma unroll
    for (int a = 0; a < 4; ++a)
      #pragma unroll
      for (int b = 0; b < 4; ++b)
        v[a][b] = tile[TADDR(r0 + 4*b + 16*a, c)];
    #pragma unroll
    for (int b = 0; b < 4; ++b){
      int tw = (j2 + 4*b) << 4;
      float2 u0,u1,u2,u3;
      BF4F(v[0][b],v[1][b],v[2][b],v[3][b],u0,u1,u2,u3);
      v[0][b] = u0;
      v[1][b] = cmulf(u1, Ws[tw]);
      v[2][b] = cmulf(u2, Ws[2*tw]);
      v[3][b] = cmulf(u3, Ws[3*tw]);
    }
    int tw3 = j2 << 6;
    #pragma unroll
    for (int a = 0; a < 4; ++a){
      float2 u0,u1,u2,u3;
      BF4F(v[a][0],v[a][1],v[a][2],v[a][3],u0,u1,u2,u3);
      tile[TADDR(r0 + 16*a, c)]      = u0;
      tile[TADDR(r0 + 16*a + 4, c)]  = cmulf(u1, Ws[tw3]);
      tile[TADDR(r0 + 16*a + 8, c)]  = cmulf(u2, Ws[2*tw3]);
      tile[TADDR(r0 + 16*a + 12, c)] = cmulf(u3, Ws[3*tw3]);
    }
  }
  __syncthreads();
  // prefetch combine's filter values (even columns only; blk!=0 path),
  // one barrier before use -> short register lifetime, latency hidden by fwd4
  float2 hfpre[8];
  size_t fbase = (size_t)blk << 13;
  if (blk != 0){
    #pragma unroll
    for (int u = 0; u < 8; ++u){
      int k2 = tid + u*CPV;
      int idx = ((k2 >> 2) << 3) | ((k2 & 3) << 1);
      hfpre[u] = HfCb[fbase + idx];
    }
  }
  // forward stage 4
  for (int k = tid; k < 2048; k += CPV){
    int c = k & 7, t = k >> 3;
    int r = 4*t;
    float2 x0 = tile[TADDR(r,c)],   x1 = tile[TADDR(r+1,c)];
    float2 x2 = tile[TADDR(r+2,c)], x3 = tile[TADDR(r+3,c)];
    float2 u0,u1,u2,u3;
    BF4F(x0,x1,x2,x3,u0,u1,u2,u3);
    tile[TADDR(r,c)] = u0; tile[TADDR(r+1,c)] = u1;
    tile[TADDR(r+2,c)] = u2; tile[TADDR(r+3,c)] = u3;
  }
  __syncthreads();
  // spectral combine on Hermitian pairs; Rdiv computed in-kernel
  if (blk != 0){
    // every pair = one even-c + one odd-c member: enumerate even c only,
    // 8 fully-active iterations, no divergence
    #pragma unroll
    for (int u = 0; u < 8; ++u){
      int k2 = tid + u*CPV;
      int p = k2 >> 2;
      int c = (k2 & 3) << 1;
      int k1 = rev4_10(p);
      int q = rev4_10((1024 - k1) & 1023);
      int colp = (blk << 3) + c;
      float2 Zk = tile[TADDR(p,c)];
      float2 Zr = tile[TADDR(q,c^1)];
      float Sre = 0.5f*(Zk.x + Zr.x);
      float Sim = 0.5f*(Zk.y - Zr.y);
      float Mre = 0.5f*(Zk.y + Zr.y);
      float Mim = 0.5f*(Zr.x - Zk.x);
      float2 hf = hfpre[u];
      int kj = unfoldc(colp);
      float cA = Ws[(k1 < 768) ? k1 : 1024 - k1].x;
      float cB = Ws[(kj < 768) ? kj : 1024 - kj].x;
      float ltl = 4.f - 2.f*cA - 2.f*cB;
      float mag2 = hf.x*hf.x + hf.y*hf.y;
      float rd = 9.5367431640625e-7f / (MU1*mag2 + MU2*ltl + MU3); // 1/N^2 folded
      float fr = rd*(Sre + hf.x*Mre + hf.y*Mim);
      float fi = rd*(Sim + hf.x*Mim - hf.y*Mre);
      float hr = hf.x*fr - hf.y*fi;
      float hi = hf.x*fi + hf.y*fr;
      tile[TADDR(p,c)]   = make_float2(fr - hi, fi + hr);
      tile[TADDR(q,c^1)] = make_float2(fr + hi, hr - fi);
    }
  } else {
    for (int k = tid; k < 8192; k += CPV){
      int p = k >> 3, c = k & 7;
      int k1 = rev4_10(p);
      int q = rev4_10((1024 - k1) & 1023);
      int colp = (blk << 3) + c;
      int cm = (colp < 2) ? c : (c ^ 1);
      int pid = (q << 3) | cm;
      if (pid < k) continue;
      float2 Zk = tile[TADDR(p,c)];
      float2 Zr = tile[TADDR(q,cm)];
      float Sre = 0.5f*(Zk.x + Zr.x);
      float Sim = 0.5f*(Zk.y - Zr.y);
      float Mre = 0.5f*(Zk.y + Zr.y);
      float Mim = 0.5f*(Zr.x - Zk.x);
      float2 hf = HfCb[fbase + k];
      int kj = unfoldc(colp);
      float cA = Ws[(k1 < 768) ? k1 : 1024 - k1].x;
      float cB = Ws[(kj < 768) ? kj : 1024 - kj].x;
      float ltl = 4.f - 2.f*cA - 2.f*cB;
      float mag2 = hf.x*hf.x + hf.y*hf.y;
      float rd = 9.5367431640625e-7f / (MU1*mag2 + MU2*ltl + MU3);
      float fr = rd*(Sre + hf.x*Mre + hf.y*Mim);
      float fi = rd*(Sim + hf.x*Mim - hf.y*Mre);
      float hr = hf.x*fr - hf.y*fi;
      float hi = hf.x*fi + hf.y*fr;
      tile[TADDR(p,c)] = make_float2(fr - hi, fi + hr);
      if (pid != k) tile[TADDR(q,cm)] = make_float2(fr + hi, hr - fi);
    }
  }
  __syncthreads();
  // inverse stages 0+1
  {
    int c = tid & 7, G = tid >> 3;
    int r0 = 16*G;
    float2 v[4][4];
    #pragma unroll
    for (int a = 0; a < 4; ++a)
      #pragma unroll
      for (int b = 0; b < 4; ++b)
        v[a][b] = tile[TADDR(r0 + 4*a + b, c)];
    #pragma unroll
    for (int a = 0; a < 4; ++a){
      float2 u0,u1,u2,u3;
      BF4I(v[a][0],v[a][1],v[a][2],v[a][3],u0,u1,u2,u3);
      v[a][0]=u0; v[a][1]=u1; v[a][2]=u2; v[a][3]=u3;
    }
    #pragma unroll
    for (int b = 0; b < 4; ++b){
      int tw = b << 6;
      float2 x0 = v[0][b];
      float2 x1 = cmulf(v[1][b], conjf(Ws[tw]));
      float2 x2 = cmulf(v[2][b], conjf(Ws[2*tw]));
      float2 x3 = cmulf(v[3][b], conjf(Ws[3*tw]));
      float2 u0,u1,u2,u3;
      BF4I(x0,x1,x2,x3,u0,u1,u2,u3);
      tile[TADDR(r0 + b, c)]      = u0;
      tile[TADDR(r0 + 4 + b, c)]  = u1;
      tile[TADDR(r0 + 8 + b, c)]  = u2;
      tile[TADDR(r0 + 12 + b, c)] = u3;
    }
  }
  __syncthreads();
  // inverse stages 2+3
  {
    int c = tid & 7, vv = tid >> 3;
    int T3 = vv >> 4, jj = vv & 15;
    int r0 = 256*T3 + jj;
    float2 v[4][4];
    #pragma unroll
    for (int a = 0; a < 4; ++a)
      #pragma unroll
      for (int b = 0; b < 4; ++b)
        v[a][b] = tile[TADDR(r0 + 16*a + 64*b, c)];
    int tw2 = jj << 4;
    #pragma unroll
    for (int b = 0; b < 4; ++b){
      float2 x0 = v[0][b];
      float2 x1 = cmulf(v[1][b], conjf(Ws[tw2]));
      float2 x2 = cmulf(v[2][b], conjf(Ws[2*tw2]));
      float2 x3 = cmulf(v[3][b], conjf(Ws[3*tw2]));
      float2 u0,u1,u2,u3;
      BF4I(x0,x1,x2,x3,u0,u1,u2,u3);
      v[0][b]=u0; v[1][b]=u1; v[2][b]=u2; v[3][b]=u3;
    }
    #pragma unroll
    for (int a = 0; a < 4; ++a){
      int tw = (jj + 16*a) << 2;
      float2 x0 = v[a][0];
      float2 x1 = cmulf(v[a][1], conjf(Ws[tw]));
      float2 x2 = cmulf(v[a][2], conjf(Ws[2*tw]));
      float2 x3 = cmulf(v[a][3], conjf(Ws[3*tw]));
      float2 u0,u1,u2,u3;
      BF4I(x0,x1,x2,x3,u0,u1,u2,u3);
      tile[TADDR(r0 + 16*a, c)]       = u0;
      tile[TADDR(r0 + 16*a + 64, c)]  = u1;
      tile[TADDR(r0 + 16*a + 128, c)] = u2;
      tile[TADDR(r0 + 16*a + 192, c)] = u3;
    }
  }
  __syncthreads();
  // inverse stage 4
  for (int k = tid; k < 2048; k += CPV){
    int c = k & 7, t = k >> 3;
    float2 x0 = tile[TADDR(t,c)];
    float2 x1 = cmulf(tile[TADDR(t+256,c)], conjf(Ws[t]));
    float2 x2 = cmulf(tile[TADDR(t+512,c)], conjf(Ws[2*t]));
    float2 x3 = cmulf(tile[TADDR(t+768,c)], conjf(Ws[3*t]));
    float2 u0,u1,u2,u3;
    BF4I(x0,x1,x2,x3,u0,u1,u2,u3);
    tile[TADDR(t,c)] = u0;     tile[TADDR(t+256,c)] = u1;
    tile[TADDR(t+512,c)] = u2; tile[TADDR(t+768,c)] = u3;
  }
  __syncthreads();
  for (int k = tid; k < 8192; k += CPV){
    int r = k >> 3, c = k & 7;
    Zp[zbase + (size_t)r*N + c] = tile[TADDR(r,c)];
  }
}

// ---------------- p5: radix-4 inverse row FFT; X,K,M,G1 updates --------------
__global__ __launch_bounds__(256) void k_p5(float2* __restrict__ Zw,
                                            float2* __restrict__ Zd,
                                            float* __restrict__ X, float* __restrict__ K,
                                            float* __restrict__ M, float* __restrict__ G1,
                                            const float* __restrict__ y,
                                            float* __restrict__ out, int writeOut,
                                            int e0, int first){
  __shared__ float2 t4[1088], bufZ[N], Ws[768];
  int tid = threadIdx.x;
  int i = blockIdx.x, ce = blockIdx.y, e = e0 + ce;
  float2* Zp = ZP(Zw, Zd, ce);
  size_t zb = (size_t)i*N;
  size_t sb = (size_t)e*NN + (size_t)i*N;
  genWs(Ws, 768, tid, 256);
  for (int k = tid; k < N; k += 256) bufZ[k] = Zp[zb + k];
  __syncthreads();
  // DIT input: t4[p] = Yhat(rev4(p)); storage Z[c] = Yhat(unfoldc(c)).
  // Scatter WRITE side (<=2-way banks) instead of gather read (16-way).
  for (int c = tid; c < N; c += 256)
    t4[A1(rev4_10(unfoldc(c)))] = bufZ[c];
  __syncthreads();
  inv_r4_row(t4, Ws, tid);
  bool rcent = (i >= 256 && i < 768);
  const float T = 1e4f;
  for (int j = tid; j < N; j += 256){
    float2 xv = t4[A1(j)];
    float x = xv.x, hx = xv.y;
    X[sb+j] = x;
    bool cent = rcent && (j >= 256 && j < 768);
    float cty  = cent ? y[(size_t)e*262144 + (size_t)(i-256)*512 + (j-256)] : 0.f;
    float kk = first ? 0.f : K[sb+j];
    float w = fmaxf(2.f*x - kk*(1.f/MU3), 0.f);
    K[sb+j] = MU3*(w - x) + kk;
    float m = first ? (cent ? cty*(MU1/(1.f+MU1)) : 0.f) : M[sb+j];
    float vdiv = cent ? (1.f/(1.f + MU1)) : (1.f/MU1);
    float v = vdiv*(2.f*MU1*hx - m + cty);
    M[sb+j] = MU1*(v - hx) + m;
    float xm = t4[A1((j-1)&1023)].x;
    float psi1 = xm - x;
    float g1 = first ? 0.f : G1[sb+j];
    float u1 = softf(2.f*psi1 - g1*(1.f/MU2), T);
    G1[sb+j] = MU2*(u1 - psi1) + g1;
    if (writeOut && cent)
      out[(size_t)e*262144 + (size_t)(i-256)*512 + (j-256)] = x;
  }
}

__global__ void k_crop(const float* __restrict__ X, float* __restrict__ out){
  int t = blockIdx.x*256 + threadIdx.x; // 8*512*512
  int e = t >> 18;
  int r = (t >> 9) & 511;
  int c = t & 511;
  out[t] = X[(size_t)e*NN + (size_t)(r+256)*N + (c+256)];
}

extern "C" void kernel_launch(void* const* d_in, const int* in_sizes, int n_in,
                              void* d_out, int out_size, void* d_ws, size_t ws_size,
                              hipStream_t stream){
  const float* y = (const float*)d_in[0];   // (8,1,512,512)
  const float* h = (const float*)d_in[1];   // (512,512)
  float* out = (float*)d_out;

  size_t fplane = (size_t)BATCH * NN;
  float* X   = (float*)d_ws;
  float* G1  = X   + fplane;
  float* K   = G1  + fplane;
  float* M   = K   + fplane;
  float* G0a = M   + fplane;
  float* G0b = G0a + fplane;
  float2* HfCb = (float2*)(G0b + fplane);
  float2* Zw   = HfCb + NN;
  size_t used = (size_t)((char*)Zw - (char*)d_ws);
  size_t zcap = (ws_size > used) ? (ws_size - used) / ((size_t)NN * sizeof(float2)) : 0;

  int CH; float2* Zd; bool needCrop;
  if (zcap >= 8){       CH = 8; Zd = Zw + 7*(size_t)NN; needCrop = true; }
  else if (zcap == 7){  CH = 8; Zd = (float2*)d_out;    needCrop = true; }
  else if (zcap >= 4){  CH = 4; Zd = Zw; needCrop = false; }
  else if (zcap >= 2){  CH = 2; Zd = Zw; needCrop = false; }
  else if (zcap >= 1){  CH = 1; Zd = Zw; needCrop = false; }
  else {                CH = 1; Zw = (float2*)d_out; Zd = Zw; needCrop = true; }

  // precompute: fft2(pad h) in Zw plane 0, filters in blocked layout
  k_build_h<<<NN/256, 256, 0, stream>>>(h, Zw);
  k_fft_row<-1><<<dim3(N,1), 256, 0, stream>>>(Zw);
  k_transpose_ip<<<dim3(528,1), dim3(32,8), 0, stream>>>(Zw);
  k_fft_row<-1><<<dim3(N,1), 256, 0, stream>>>(Zw);
  k_filters2<<<NN/256, 256, 0, stream>>>(Zw, HfCb);

  for (int t = 0; t < 20; ++t){
    const float* G0r = (t & 1) ? G0b : G0a;
    float*       G0w = (t & 1) ? G0a : G0b;
    int mode = (t == 0) ? 2 : ((t == 1) ? 1 : 0);
    int wo = (t == 19 && !needCrop) ? 1 : 0;
    for (int e0 = 0; e0 < BATCH; e0 += CH){
      k_pA<<<dim3(N,CH), 256, 0, stream>>>(X, G0r, G0w, G1, K, M, y, Zw, Zd, e0, mode);
      k_colpass<<<dim3(128,CH), CPV, 0, stream>>>(Zw, Zd, HfCb);
      k_p5<<<dim3(N,CH), 256, 0, stream>>>(Zw, Zd, X, K, M, G1, y, out, wo, e0, (t==0)?1:0);
    }
  }
  if (needCrop)
    k_crop<<<(BATCH*512*512)/256, 256, 0, stream>>>(X, out);
}

// Round 15
// 3315.718 us; speedup vs baseline: 1.0091x; 1.0091x over previous
//
#include <hip/hip_runtime.h>
#include <math.h>

#define N 1024
#define NN (1024*1024)
#define BATCH 8

static constexpr float MU1 = 1e-6f, MU2 = 1e-5f, MU3 = 1e-5f;

__device__ __forceinline__ float2 cmulf(float2 a, float2 b){
  return make_float2(a.x*b.x - a.y*b.y, a.x*b.y + a.y*b.x);
}
__device__ __forceinline__ float2 conjf(float2 a){ return make_float2(a.x, -a.y); }
__device__ __forceinline__ float softf(float v, float T){
  float a = fmaxf(fabsf(v) - T, 0.f);
  return copysignf(a, v);
}
__device__ __forceinline__ int rev4_10(int p){
  return ((p&3)<<8) | (((p>>2)&3)<<6) | (((p>>4)&3)<<4) | (((p>>6)&3)<<2) | ((p>>8)&3);
}
__device__ __forceinline__ int foldc(int k){
  if (k == 0) return 0;
  if (k == 512) return 1;
  return (k < 512) ? 2*k : 2*(1024-k)+1;
}
__device__ __forceinline__ int unfoldc(int c){
  if (c < 2) return c ? 512 : 0;
  return (c & 1) ? 1024 - ((c-1)>>1) : (c>>1);
}
__device__ __forceinline__ float2* ZP(float2* Zw, float2* Zd, int ce){
  return (ce == 7) ? Zd : (Zw + (size_t)ce * NN);
}

#define BF4F(x0,x1,x2,x3,u0,u1,u2,u3) { \
  float2 t02p = make_float2((x0).x+(x2).x, (x0).y+(x2).y); \
  float2 t02m = make_float2((x0).x-(x2).x, (x0).y-(x2).y); \
  float2 t13p = make_float2((x1).x+(x3).x, (x1).y+(x3).y); \
  float2 t13m = make_float2((x1).x-(x3).x, (x1).y-(x3).y); \
  u0 = make_float2(t02p.x+t13p.x, t02p.y+t13p.y); \
  u2 = make_float2(t02p.x-t13p.x, t02p.y-t13p.y); \
  u1 = make_float2(t02m.x+t13m.y, t02m.y-t13m.x); \
  u3 = make_float2(t02m.x-t13m.y, t02m.y+t13m.x); }
#define BF4I(x0,x1,x2,x3,u0,u1,u2,u3) { \
  float2 t02p = make_float2((x0).x+(x2).x, (x0).y+(x2).y); \
  float2 t02m = make_float2((x0).x-(x2).x, (x0).y-(x2).y); \
  float2 t13p = make_float2((x1).x+(x3).x, (x1).y+(x3).y); \
  float2 t13m = make_float2((x1).x-(x3).x, (x1).y-(x3).y); \
  u0 = make_float2(t02p.x+t13p.x, t02p.y+t13p.y); \
  u2 = make_float2(t02p.x-t13p.x, t02p.y-t13p.y); \
  u1 = make_float2(t02m.x-t13m.y, t02m.y+t13m.x); \
  u3 = make_float2(t02m.x+t13m.y, t02m.y-t13m.x); }

// generate Ws[0..cnt) = exp(-2*pi*i*j/1024) in LDS
__device__ __forceinline__ void genWs(float2* Ws, int cnt, int tid, int nthr){
  for (int j = tid; j < cnt; j += nthr){
    double a = (double)j * (-M_PI / 512.0);
    float s, c;
    sincosf((float)a, &s, &c);
    Ws[j] = make_float2(c, s);
  }
}

// ---------------- 1024-pt Stockham radix-2 FFT (precompute row passes) ------
template<int DIR>
__device__ __forceinline__ void fft1024(float2* bufA, float2* bufB,
                                        const float2* Ws, int tid){
  float2* cur = bufA; float2* oth = bufB;
  int s = 1;
  for (int st = 0; st < 10; ++st){
    int m = 512 >> st;
    #pragma unroll
    for (int bb = 0; bb < 2; ++bb){
      int b = tid + bb*256;
      int p = b >> st;
      int q = b & (s-1);
      float2 a = cur[b];
      float2 c = cur[b + 512];
      float2 w = Ws[b & ~(s-1)];
      if (DIR > 0) w.y = -w.y;
      float2 d = make_float2(a.x - c.x, a.y - c.y);
      oth[q + s*(2*p)]   = make_float2(a.x + c.x, a.y + c.y);
      oth[q + s*(2*p+1)] = cmulf(d, w);
    }
    __syncthreads();
    float2* t = cur; cur = oth; oth = t;
    s <<= 1;
  }
}

// ======== in-place single-row radix-4 FFT, 256 threads, 5 syncs =============
#define A1(p) ((p) + ((p)>>4))    // padded addr, uniform 4/bank-pair per stage

__device__ __forceinline__ void fwd_r4_row(float2* t4, const float2* Ws, int tid){
  #pragma unroll
  for (int s = 0; s < 5; ++s){
    int log2L = 8 - 2*s;
    int L = 1 << log2L;
    int j = tid & (L-1);
    int base = ((tid >> log2L) << (log2L+2)) + j;
    int tw = j << (2*s);
    float2 x0 = t4[A1(base)],     x1 = t4[A1(base+L)],
           x2 = t4[A1(base+2*L)], x3 = t4[A1(base+3*L)];
    float2 u0,u1,u2,u3;
    BF4F(x0,x1,x2,x3,u0,u1,u2,u3);
    t4[A1(base)]     = u0;
    t4[A1(base+L)]   = cmulf(u1, Ws[tw]);
    t4[A1(base+2*L)] = cmulf(u2, Ws[2*tw]);
    t4[A1(base+3*L)] = cmulf(u3, Ws[3*tw]);
    __syncthreads();
  }
}

__device__ __forceinline__ void inv_r4_row(float2* t4, const float2* Ws, int tid){
  #pragma unroll
  for (int s = 0; s < 5; ++s){
    int H = 1 << (2*s);
    int j = tid & (H-1);
    int base = ((tid >> (2*s)) << (2*s+2)) + j;
    int tw = j << (8 - 2*s);
    float2 x0 = t4[A1(base)];
    float2 x1 = cmulf(t4[A1(base+H)],   conjf(Ws[tw]));
    float2 x2 = cmulf(t4[A1(base+2*H)], conjf(Ws[2*tw]));
    float2 x3 = cmulf(t4[A1(base+3*H)], conjf(Ws[3*tw]));
    float2 u0,u1,u2,u3;
    BF4I(x0,x1,x2,x3,u0,u1,u2,u3);
    t4[A1(base)] = u0;     t4[A1(base+H)] = u1;
    t4[A1(base+2*H)] = u2; t4[A1(base+3*H)] = u3;
    __syncthreads();
  }
}

// ---------------- precompute ----------------
__global__ void k_build_h(const float* __restrict__ h, float2* __restrict__ Z){
  int idx = blockIdx.x*256 + threadIdx.x; // NN
  int i = idx >> 10, j = idx & 1023;
  float v = 0.f;
  if (i >= 256 && i < 768 && j >= 256 && j < 768)
    v = h[(i-256)*512 + (j-256)];
  Z[idx] = make_float2(v, 0.f);
}

template<int DIR>
__global__ __launch_bounds__(256) void k_fft_row(float2* Z){
  __shared__ float2 bufA[N], bufB[N], Ws[512];
  int tid = threadIdx.x;
  size_t base = ((size_t)blockIdx.y * N + blockIdx.x) * N;
  genWs(Ws, 512, tid, 256);
  for (int k = tid; k < N; k += 256) bufA[k] = Z[base + k];
  __syncthreads();
  fft1024<DIR>(bufA, bufB, Ws, tid);
  for (int k = tid; k < N; k += 256) Z[base + k] = bufA[k];
}

__global__ void k_transpose_ip(float2* Z){
  __shared__ float2 ta[32][33], tb[32][33];
  int t = blockIdx.x, ti = 0;
  while (t >= 32 - ti){ t -= 32 - ti; ti++; }
  int tj = ti + t;
  size_t base = (size_t)blockIdx.y * NN;
  int ra = ti*32, ca = tj*32;
  for (int k = threadIdx.y; k < 32; k += 8){
    ta[k][threadIdx.x] = Z[base + (size_t)(ra+k)*N + ca + threadIdx.x];
    if (ti != tj)
      tb[k][threadIdx.x] = Z[base + (size_t)(ca+k)*N + ra + threadIdx.x];
  }
  __syncthreads();
  for (int k = threadIdx.y; k < 32; k += 8){
    Z[base + (size_t)(ra+k)*N + ca + threadIdx.x] = (ti!=tj) ? tb[threadIdx.x][k]
                                                             : ta[threadIdx.x][k];
    if (ti != tj)
      Z[base + (size_t)(ca+k)*N + ra + threadIdx.x] = ta[threadIdx.x][k];
  }
}

// ZT[idx] = fft2(pad h) at (k_j = idx>>10, k_i = idx&1023).
// Blocked 8-col colpass layout: HfCb[blk][p][c], k_i=rev4(p), k_j=unfold(blk*8+c).
__global__ void k_filters2(const float2* __restrict__ ZT, float2* __restrict__ HfCb){
  int id = blockIdx.x*256 + threadIdx.x; // NN
  int blk = id >> 13;
  int rem = id & 8191;
  int p = rem >> 3, c = rem & 7;
  int colp = (blk << 3) | c;
  int ki = rev4_10(p);
  int kj = unfoldc(colp);
  float2 v = ZT[((size_t)kj << 10) | (size_t)ki];
  float sgn = ((ki + kj) & 1) ? -1.f : 1.f;
  HfCb[id] = make_float2(sgn*v.x, sgn*v.y);
}

// ---------------- pA: fused G0-update + s-build + radix-4 fwd row FFT --------
// mode 0: normal. mode 1 (t==1): G0r treated as zero. mode 2 (t==0): all state
// zero, z = i*M0(y), no state reads/writes.
__global__ __launch_bounds__(256) void k_pA(const float* __restrict__ X,
                                            const float* __restrict__ G0r,
                                            float* __restrict__ G0w,
                                            const float* __restrict__ G1,
                                            const float* __restrict__ K,
                                            const float* __restrict__ M,
                                            const float* __restrict__ y,
                                            float2* __restrict__ Zw,
                                            float2* __restrict__ Zd,
                                            int e0, int mode){
  __shared__ float2 t4[1088], Ws[768];
  int tid = threadIdx.x;
  int bid = blockIdx.x;
  int i = ((bid & 7) << 7) + (bid >> 3);   // XCD row-chunk swizzle
  int ce = blockIdx.y, e = e0 + ce;
  size_t eb  = (size_t)e*NN;
  size_t rb  = eb + (size_t)i*N;
  size_t rbm = eb + (size_t)((i-1)&1023)*N;
  size_t rbp = eb + (size_t)((i+1)&1023)*N;
  float2* Zp = ZP(Zw, Zd, ce);
  size_t zb  = (size_t)i*N;
  genWs(Ws, 768, tid, 256);
  const float T = 1e4f;                    // TAU/MU2
  if (mode == 2){
    bool rcent = (i >= 256 && i < 768);
    for (int j = tid; j < N; j += 256){
      float m0 = 0.f;
      if (rcent && j >= 256 && j < 768)
        m0 = y[(size_t)e*262144 + (size_t)(i-256)*512 + (j-256)] * (MU1/(1.f + MU1));
      t4[A1(j)] = make_float2(0.f, m0);
    }
  } else {
    for (int j = tid; j < N; j += 256){
      float xm = X[rbm+j], x = X[rb+j], xp = X[rbp+j];
      float psi0  = xm - x;
      float psi0p = x - xp;                // psi0 at row i+1
      float g0  = (mode == 1) ? 0.f : G0r[rb+j];
      float g0p = (mode == 1) ? 0.f : G0r[rbp+j];
      float u0  = softf(2.f*psi0  - g0 *(1.f/MU2), T);
      float u0p = softf(2.f*psi0p - g0p*(1.f/MU2), T);
      float g0n  = MU2*(u0  - psi0 ) + g0;
      float g0np = MU2*(u0p - psi0p) + g0p;
      G0w[rb+j] = g0n;
      int jp = (j+1) & 1023;
      float s = K[rb+j] + (g0np - g0n) + (G1[rb+jp] - G1[rb+j]);
      t4[A1(j)] = make_float2(s, M[rb+j]);
    }
  }
  __syncthreads();
  fwd_r4_row(t4, Ws, tid);
  // storage order: Z[c] = F(unfoldc(c)); DIF left F(k) at pos rev4(k)
  for (int c = tid; c < N; c += 256)
    Zp[zb + c] = t4[A1(rev4_10(unfoldc(c)))];
}

// ---------------- fused column pass: radix-4 (2 stages/sync) + combine -------
#define TADDR(r,c) ((((r)*9) + (c)) ^ (((r) & 16) >> 1))
#define CPV 512
__global__ __launch_bounds__(CPV) void k_colpass(float2* __restrict__ Zw,
    float2* __restrict__ Zd, const float2* __restrict__ HfCb){
  __shared__ float2 tile[9216];
  __shared__ float2 Ws[768];
  int tid = threadIdx.x;
  int blk = blockIdx.x;              // 128 col-groups of 8
  float2* Zp = ZP(Zw, Zd, blockIdx.y);
  size_t zbase = (size_t)(blk<<3);
  genWs(Ws, 768, tid, CPV);
  for (int k = tid; k < 8192; k += CPV){
    int r = k >> 3, c = k & 7;
    tile[TADDR(r,c)] = Zp[zbase + (size_t)r*N + c];
  }
  __syncthreads();
  // forward stages 0+1
  {
    int c = tid & 7, j2 = tid >> 3;
    float2 v[4][4];
    #pragma unroll
    for (int a = 0; a < 4; ++a)
      #pragma unroll
      for (int b = 0; b < 4; ++b)
        v[a][b] = tile[TADDR(j2 + 64*b + 256*a, c)];
    #pragma unroll
    for (int b = 0; b < 4; ++b){
      int j1 = j2 + 64*b;
      float2 u0,u1,u2,u3;
      BF4F(v[0][b],v[1][b],v[2][b],v[3][b],u0,u1,u2,u3);
      v[0][b] = u0;
      v[1][b] = cmulf(u1, Ws[j1]);
      v[2][b] = cmulf(u2, Ws[2*j1]);
      v[3][b] = cmulf(u3, Ws[3*j1]);
    }
    int tw = j2 << 2;
    #pragma unroll
    for (int a = 0; a < 4; ++a){
      float2 u0,u1,u2,u3;
      BF4F(v[a][0],v[a][1],v[a][2],v[a][3],u0,u1,u2,u3);
      tile[TADDR(j2 + 256*a, c)]       = u0;
      tile[TADDR(j2 + 64 + 256*a, c)]  = cmulf(u1, Ws[tw]);
      tile[TADDR(j2 + 128 + 256*a, c)] = cmulf(u2, Ws[2*tw]);
      tile[TADDR(j2 + 192 + 256*a, c)] = cmulf(u3, Ws[3*tw]);
    }
  }
  __syncthreads();
  // forward stages 2+3
  {
    int c = tid & 7, vv = tid >> 3;
    int B2 = vv >> 2, j2 = vv & 3;
    int r0 = 64*B2 + j2;
    float2 v[4][4];
    #pragma unroll
    for (int a = 0; a < 4; ++a)
      #pragma unroll
      for (int b = 0; b < 4; ++b)
        v[a][b] = tile[TADDR(r0 + 4*b + 16*a, c)];
    #pragma unroll
    for (int b = 0; b < 4; ++b){
      int tw = (j2 + 4*b) << 4;
      float2 u0,u1,u2,u3;
      BF4F(v[0][b],v[1][b],v[2][b],v[3][b],u0,u1,u2,u3);
      v[0][b] = u0;
      v[1][b] = cmulf(u1, Ws[tw]);
      v[2][b] = cmulf(u2, Ws[2*tw]);
      v[3][b] = cmulf(u3, Ws[3*tw]);
    }
    int tw3 = j2 << 6;
    #pragma unroll
    for (int a = 0; a < 4; ++a){
      float2 u0,u1,u2,u3;
      BF4F(v[a][0],v[a][1],v[a][2],v[a][3],u0,u1,u2,u3);
      tile[TADDR(r0 + 16*a, c)]      = u0;
      tile[TADDR(r0 + 16*a + 4, c)]  = cmulf(u1, Ws[tw3]);
      tile[TADDR(r0 + 16*a + 8, c)]  = cmulf(u2, Ws[2*tw3]);
      tile[TADDR(r0 + 16*a + 12, c)] = cmulf(u3, Ws[3*tw3]);
    }
  }
  __syncthreads();
  // prefetch combine's filter values (even columns only; blk!=0 path),
  // one barrier before use -> short register lifetime, latency hidden by fwd4
  float2 hfpre[8];
  size_t fbase = (size_t)blk << 13;
  if (blk != 0){
    #pragma unroll
    for (int u = 0; u < 8; ++u){
      int k2 = tid + u*CPV;
      int idx = ((k2 >> 2) << 3) | ((k2 & 3) << 1);
      hfpre[u] = HfCb[fbase + idx];
    }
  }
  // forward stage 4
  for (int k = tid; k < 2048; k += CPV){
    int c = k & 7, t = k >> 3;
    int r = 4*t;
    float2 x0 = tile[TADDR(r,c)],   x1 = tile[TADDR(r+1,c)];
    float2 x2 = tile[TADDR(r+2,c)], x3 = tile[TADDR(r+3,c)];
    float2 u0,u1,u2,u3;
    BF4F(x0,x1,x2,x3,u0,u1,u2,u3);
    tile[TADDR(r,c)] = u0; tile[TADDR(r+1,c)] = u1;
    tile[TADDR(r+2,c)] = u2; tile[TADDR(r+3,c)] = u3;
  }
  __syncthreads();
  // spectral combine on Hermitian pairs; Rdiv computed in-kernel
  if (blk != 0){
    #pragma unroll
    for (int u = 0; u < 8; ++u){
      int k2 = tid + u*CPV;
      int p = k2 >> 2;
      int c = (k2 & 3) << 1;
      int k1 = rev4_10(p);
      int q = rev4_10((1024 - k1) & 1023);
      int colp = (blk << 3) + c;
      float2 Zk = tile[TADDR(p,c)];
      float2 Zr = tile[TADDR(q,c^1)];
      float Sre = 0.5f*(Zk.x + Zr.x);
      float Sim = 0.5f*(Zk.y - Zr.y);
      float Mre = 0.5f*(Zk.y + Zr.y);
      float Mim = 0.5f*(Zr.x - Zk.x);
      float2 hf = hfpre[u];
      int kj = unfoldc(colp);
      float cA = Ws[(k1 < 768) ? k1 : 1024 - k1].x;
      float cB = Ws[(kj < 768) ? kj : 1024 - kj].x;
      float ltl = 4.f - 2.f*cA - 2.f*cB;
      float mag2 = hf.x*hf.x + hf.y*hf.y;
      float rd = 9.5367431640625e-7f / (MU1*mag2 + MU2*ltl + MU3); // 1/N^2 folded
      float fr = rd*(Sre + hf.x*Mre + hf.y*Mim);
      float fi = rd*(Sim + hf.x*Mim - hf.y*Mre);
      float hr = hf.x*fr - hf.y*fi;
      float hi = hf.x*fi + hf.y*fr;
      tile[TADDR(p,c)]   = make_float2(fr - hi, fi + hr);
      tile[TADDR(q,c^1)] = make_float2(fr + hi, hr - fi);
    }
  } else {
    for (int k = tid; k < 8192; k += CPV){
      int p = k >> 3, c = k & 7;
      int k1 = rev4_10(p);
      int q = rev4_10((1024 - k1) & 1023);
      int colp = (blk << 3) + c;
      int cm = (colp < 2) ? c : (c ^ 1);
      int pid = (q << 3) | cm;
      if (pid < k) continue;
      float2 Zk = tile[TADDR(p,c)];
      float2 Zr = tile[TADDR(q,cm)];
      float Sre = 0.5f*(Zk.x + Zr.x);
      float Sim = 0.5f*(Zk.y - Zr.y);
      float Mre = 0.5f*(Zk.y + Zr.y);
      float Mim = 0.5f*(Zr.x - Zk.x);
      float2 hf = HfCb[fbase + k];
      int kj = unfoldc(colp);
      float cA = Ws[(k1 < 768) ? k1 : 1024 - k1].x;
      float cB = Ws[(kj < 768) ? kj : 1024 - kj].x;
      float ltl = 4.f - 2.f*cA - 2.f*cB;
      float mag2 = hf.x*hf.x + hf.y*hf.y;
      float rd = 9.5367431640625e-7f / (MU1*mag2 + MU2*ltl + MU3);
      float fr = rd*(Sre + hf.x*Mre + hf.y*Mim);
      float fi = rd*(Sim + hf.x*Mim - hf.y*Mre);
      float hr = hf.x*fr - hf.y*fi;
      float hi = hf.x*fi + hf.y*fr;
      tile[TADDR(p,c)] = make_float2(fr - hi, fi + hr);
      if (pid != k) tile[TADDR(q,cm)] = make_float2(fr + hi, hr - fi);
    }
  }
  __syncthreads();
  // inverse stages 0+1
  {
    int c = tid & 7, G = tid >> 3;
    int r0 = 16*G;
    float2 v[4][4];
    #pragma unroll
    for (int a = 0; a < 4; ++a)
      #pragma unroll
      for (int b = 0; b < 4; ++b)
        v[a][b] = tile[TADDR(r0 + 4*a + b, c)];
    #pragma unroll
    for (int a = 0; a < 4; ++a){
      float2 u0,u1,u2,u3;
      BF4I(v[a][0],v[a][1],v[a][2],v[a][3],u0,u1,u2,u3);
      v[a][0]=u0; v[a][1]=u1; v[a][2]=u2; v[a][3]=u3;
    }
    #pragma unroll
    for (int b = 0; b < 4; ++b){
      int tw = b << 6;
      float2 x0 = v[0][b];
      float2 x1 = cmulf(v[1][b], conjf(Ws[tw]));
      float2 x2 = cmulf(v[2][b], conjf(Ws[2*tw]));
      float2 x3 = cmulf(v[3][b], conjf(Ws[3*tw]));
      float2 u0,u1,u2,u3;
      BF4I(x0,x1,x2,x3,u0,u1,u2,u3);
      tile[TADDR(r0 + b, c)]      = u0;
      tile[TADDR(r0 + 4 + b, c)]  = u1;
      tile[TADDR(r0 + 8 + b, c)]  = u2;
      tile[TADDR(r0 + 12 + b, c)] = u3;
    }
  }
  __syncthreads();
  // inverse stages 2+3
  {
    int c = tid & 7, vv = tid >> 3;
    int T3 = vv >> 4, jj = vv & 15;
    int r0 = 256*T3 + jj;
    float2 v[4][4];
    #pragma unroll
    for (int a = 0; a < 4; ++a)
      #pragma unroll
      for (int b = 0; b < 4; ++b)
        v[a][b] = tile[TADDR(r0 + 16*a + 64*b, c)];
    int tw2 = jj << 4;
    #pragma unroll
    for (int b = 0; b < 4; ++b){
      float2 x0 = v[0][b];
      float2 x1 = cmulf(v[1][b], conjf(Ws[tw2]));
      float2 x2 = cmulf(v[2][b], conjf(Ws[2*tw2]));
      float2 x3 = cmulf(v[3][b], conjf(Ws[3*tw2]));
      float2 u0,u1,u2,u3;
      BF4I(x0,x1,x2,x3,u0,u1,u2,u3);
      v[0][b]=u0; v[1][b]=u1; v[2][b]=u2; v[3][b]=u3;
    }
    #pragma unroll
    for (int a = 0; a < 4; ++a){
      int tw = (jj + 16*a) << 2;
      float2 x0 = v[a][0];
      float2 x1 = cmulf(v[a][1], conjf(Ws[tw]));
      float2 x2 = cmulf(v[a][2], conjf(Ws[2*tw]));
      float2 x3 = cmulf(v[a][3], conjf(Ws[3*tw]));
      float2 u0,u1,u2,u3;
      BF4I(x0,x1,x2,x3,u0,u1,u2,u3);
      tile[TADDR(r0 + 16*a, c)]       = u0;
      tile[TADDR(r0 + 16*a + 64, c)]  = u1;
      tile[TADDR(r0 + 16*a + 128, c)] = u2;
      tile[TADDR(r0 + 16*a + 192, c)] = u3;
    }
  }
  __syncthreads();
  // inverse stage 4
  for (int k = tid; k < 2048; k += CPV){
    int c = k & 7, t = k >> 3;
    float2 x0 = tile[TADDR(t,c)];
    float2 x1 = cmulf(tile[TADDR(t+256,c)], conjf(Ws[t]));
    float2 x2 = cmulf(tile[TADDR(t+512,c)], conjf(Ws[2*t]));
    float2 x3 = cmulf(tile[TADDR(t+768,c)], conjf(Ws[3*t]));
    float2 u0,u1,u2,u3;
    BF4I(x0,x1,x2,x3,u0,u1,u2,u3);
    tile[TADDR(t,c)] = u0;     tile[TADDR(t+256,c)] = u1;
    tile[TADDR(t+512,c)] = u2; tile[TADDR(t+768,c)] = u3;
  }
  __syncthreads();
  for (int k = tid; k < 8192; k += CPV){
    int r = k >> 3, c = k & 7;
    Zp[zbase + (size_t)r*N + c] = tile[TADDR(r,c)];
  }
}

// ---------------- p5: radix-4 inverse row FFT; X,K,M,G1 updates --------------
__global__ __launch_bounds__(256) void k_p5(float2* __restrict__ Zw,
                                            float2* __restrict__ Zd,
                                            float* __restrict__ X, float* __restrict__ K,
                                            float* __restrict__ M, float* __restrict__ G1,
                                            const float* __restrict__ y,
                                            float* __restrict__ out, int writeOut,
                                            int e0, int first){
  __shared__ float2 t4[1088], Ws[768];
  int tid = threadIdx.x;
  int i = blockIdx.x, ce = blockIdx.y, e = e0 + ce;
  float2* Zp = ZP(Zw, Zd, ce);
  size_t zb = (size_t)i*N;
  size_t sb = (size_t)e*NN + (size_t)i*N;
  genWs(Ws, 768, tid, 256);
  // fused global load + fold/digit-reversal scatter (no staging buffer):
  // t4[A1(rev4(unfold(c)))] = Z[c]  ==  t4[A1(p)] = Z[foldc(rev4(p))]
  for (int c = tid; c < N; c += 256)
    t4[A1(rev4_10(unfoldc(c)))] = Zp[zb + c];
  __syncthreads();
  inv_r4_row(t4, Ws, tid);
  bool rcent = (i >= 256 && i < 768);
  const float T = 1e4f;
  for (int j = tid; j < N; j += 256){
    float2 xv = t4[A1(j)];
    float x = xv.x, hx = xv.y;
    X[sb+j] = x;
    bool cent = rcent && (j >= 256 && j < 768);
    float cty  = cent ? y[(size_t)e*262144 + (size_t)(i-256)*512 + (j-256)] : 0.f;
    float kk = first ? 0.f : K[sb+j];
    float w = fmaxf(2.f*x - kk*(1.f/MU3), 0.f);
    K[sb+j] = MU3*(w - x) + kk;
    float m = first ? (cent ? cty*(MU1/(1.f+MU1)) : 0.f) : M[sb+j];
    float vdiv = cent ? (1.f/(1.f + MU1)) : (1.f/MU1);
    float v = vdiv*(2.f*MU1*hx - m + cty);
    M[sb+j] = MU1*(v - hx) + m;
    float xm = t4[A1((j-1)&1023)].x;
    float psi1 = xm - x;
    float g1 = first ? 0.f : G1[sb+j];
    float u1 = softf(2.f*psi1 - g1*(1.f/MU2), T);
    G1[sb+j] = MU2*(u1 - psi1) + g1;
    if (writeOut && cent)
      out[(size_t)e*262144 + (size_t)(i-256)*512 + (j-256)] = x;
  }
}

__global__ void k_crop(const float* __restrict__ X, float* __restrict__ out){
  int t = blockIdx.x*256 + threadIdx.x; // 8*512*512
  int e = t >> 18;
  int r = (t >> 9) & 511;
  int c = t & 511;
  out[t] = X[(size_t)e*NN + (size_t)(r+256)*N + (c+256)];
}

extern "C" void kernel_launch(void* const* d_in, const int* in_sizes, int n_in,
                              void* d_out, int out_size, void* d_ws, size_t ws_size,
                              hipStream_t stream){
  const float* y = (const float*)d_in[0];   // (8,1,512,512)
  const float* h = (const float*)d_in[1];   // (512,512)
  float* out = (float*)d_out;

  size_t fplane = (size_t)BATCH * NN;
  float* X   = (float*)d_ws;
  float* G1  = X   + fplane;
  float* K   = G1  + fplane;
  float* M   = K   + fplane;
  float* G0a = M   + fplane;
  float* G0b = G0a + fplane;
  float2* HfCb = (float2*)(G0b + fplane);
  float2* Zw   = HfCb + NN;
  size_t used = (size_t)((char*)Zw - (char*)d_ws);
  size_t zcap = (ws_size > used) ? (ws_size - used) / ((size_t)NN * sizeof(float2)) : 0;

  int CH; float2* Zd; bool needCrop;
  if (zcap >= 8){       CH = 8; Zd = Zw + 7*(size_t)NN; needCrop = true; }
  else if (zcap == 7){  CH = 8; Zd = (float2*)d_out;    needCrop = true; }
  else if (zcap >= 4){  CH = 4; Zd = Zw; needCrop = false; }
  else if (zcap >= 2){  CH = 2; Zd = Zw; needCrop = false; }
  else if (zcap >= 1){  CH = 1; Zd = Zw; needCrop = false; }
  else {                CH = 1; Zw = (float2*)d_out; Zd = Zw; needCrop = true; }

  // precompute: fft2(pad h) in Zw plane 0, filters in blocked layout
  k_build_h<<<NN/256, 256, 0, stream>>>(h, Zw);
  k_fft_row<-1><<<dim3(N,1), 256, 0, stream>>>(Zw);
  k_transpose_ip<<<dim3(528,1), dim3(32,8), 0, stream>>>(Zw);
  k_fft_row<-1><<<dim3(N,1), 256, 0, stream>>>(Zw);
  k_filters2<<<NN/256, 256, 0, stream>>>(Zw, HfCb);

  for (int t = 0; t < 20; ++t){
    const float* G0r = (t & 1) ? G0b : G0a;
    float*       G0w = (t & 1) ? G0a : G0b;
    int mode = (t == 0) ? 2 : ((t == 1) ? 1 : 0);
    int wo = (t == 19 && !needCrop) ? 1 : 0;
    for (int e0 = 0; e0 < BATCH; e0 += CH){
      k_pA<<<dim3(N,CH), 256, 0, stream>>>(X, G0r, G0w, G1, K, M, y, Zw, Zd, e0, mode);
      k_colpass<<<dim3(128,CH), CPV, 0, stream>>>(Zw, Zd, HfCb);
      k_p5<<<dim3(N,CH), 256, 0, stream>>>(Zw, Zd, X, K, M, G1, y, out, wo, e0, (t==0)?1:0);
    }
  }
  if (needCrop)
    k_crop<<<(BATCH*512*512)/256, 256, 0, stream>>>(X, out);
}

// Round 16
// 3275.409 us; speedup vs baseline: 1.0215x; 1.0123x over previous
//
#include <hip/hip_runtime.h>
#include <math.h>

#define N 1024
#define NN (1024*1024)
#define BATCH 8

static constexpr float MU1 = 1e-6f, MU2 = 1e-5f, MU3 = 1e-5f;

__device__ __forceinline__ float2 cmulf(float2 a, float2 b){
  return make_float2(a.x*b.x - a.y*b.y, a.x*b.y + a.y*b.x);
}
__device__ __forceinline__ float2 conjf(float2 a){ return make_float2(a.x, -a.y); }
__device__ __forceinline__ float softf(float v, float T){
  float a = fmaxf(fabsf(v) - T, 0.f);
  return copysignf(a, v);
}
__device__ __forceinline__ int rev4_10(int p){
  return ((p&3)<<8) | (((p>>2)&3)<<6) | (((p>>4)&3)<<4) | (((p>>6)&3)<<2) | ((p>>8)&3);
}
__device__ __forceinline__ int foldc(int k){
  if (k == 0) return 0;
  if (k == 512) return 1;
  return (k < 512) ? 2*k : 2*(1024-k)+1;
}
__device__ __forceinline__ int unfoldc(int c){
  if (c < 2) return c ? 512 : 0;
  return (c & 1) ? 1024 - ((c-1)>>1) : (c>>1);
}
__device__ __forceinline__ float2* ZP(float2* Zw, float2* Zd, int ce){
  return (ce == 7) ? Zd : (Zw + (size_t)ce * NN);
}

#define BF4F(x0,x1,x2,x3,u0,u1,u2,u3) { \
  float2 t02p = make_float2((x0).x+(x2).x, (x0).y+(x2).y); \
  float2 t02m = make_float2((x0).x-(x2).x, (x0).y-(x2).y); \
  float2 t13p = make_float2((x1).x+(x3).x, (x1).y+(x3).y); \
  float2 t13m = make_float2((x1).x-(x3).x, (x1).y-(x3).y); \
  u0 = make_float2(t02p.x+t13p.x, t02p.y+t13p.y); \
  u2 = make_float2(t02p.x-t13p.x, t02p.y-t13p.y); \
  u1 = make_float2(t02m.x+t13m.y, t02m.y-t13m.x); \
  u3 = make_float2(t02m.x-t13m.y, t02m.y+t13m.x); }
#define BF4I(x0,x1,x2,x3,u0,u1,u2,u3) { \
  float2 t02p = make_float2((x0).x+(x2).x, (x0).y+(x2).y); \
  float2 t02m = make_float2((x0).x-(x2).x, (x0).y-(x2).y); \
  float2 t13p = make_float2((x1).x+(x3).x, (x1).y+(x3).y); \
  float2 t13m = make_float2((x1).x-(x3).x, (x1).y-(x3).y); \
  u0 = make_float2(t02p.x+t13p.x, t02p.y+t13p.y); \
  u2 = make_float2(t02p.x-t13p.x, t02p.y-t13p.y); \
  u1 = make_float2(t02m.x-t13m.y, t02m.y+t13m.x); \
  u3 = make_float2(t02m.x+t13m.y, t02m.y-t13m.x); }

// generate Ws[0..cnt) = exp(-2*pi*i*j/1024) in LDS
__device__ __forceinline__ void genWs(float2* Ws, int cnt, int tid, int nthr){
  for (int j = tid; j < cnt; j += nthr){
    double a = (double)j * (-M_PI / 512.0);
    float s, c;
    sincosf((float)a, &s, &c);
    Ws[j] = make_float2(c, s);
  }
}

// ---------------- 1024-pt Stockham radix-2 FFT (precompute row passes) ------
template<int DIR>
__device__ __forceinline__ void fft1024(float2* bufA, float2* bufB,
                                        const float2* Ws, int tid){
  float2* cur = bufA; float2* oth = bufB;
  int s = 1;
  for (int st = 0; st < 10; ++st){
    int m = 512 >> st;
    #pragma unroll
    for (int bb = 0; bb < 2; ++bb){
      int b = tid + bb*256;
      int p = b >> st;
      int q = b & (s-1);
      float2 a = cur[b];
      float2 c = cur[b + 512];
      float2 w = Ws[b & ~(s-1)];
      if (DIR > 0) w.y = -w.y;
      float2 d = make_float2(a.x - c.x, a.y - c.y);
      oth[q + s*(2*p)]   = make_float2(a.x + c.x, a.y + c.y);
      oth[q + s*(2*p+1)] = cmulf(d, w);
    }
    __syncthreads();
    float2* t = cur; cur = oth; oth = t;
    s <<= 1;
  }
}

// ======== in-place single-row radix-4 FFT, 256 threads, 5 syncs =============
#define A1(p) ((p) + ((p)>>4))    // padded addr, uniform 4/bank-pair per stage

__device__ __forceinline__ void fwd_r4_row(float2* t4, const float2* Ws, int tid){
  #pragma unroll
  for (int s = 0; s < 5; ++s){
    int log2L = 8 - 2*s;
    int L = 1 << log2L;
    int j = tid & (L-1);
    int base = ((tid >> log2L) << (log2L+2)) + j;
    int tw = j << (2*s);
    float2 x0 = t4[A1(base)],     x1 = t4[A1(base+L)],
           x2 = t4[A1(base+2*L)], x3 = t4[A1(base+3*L)];
    float2 u0,u1,u2,u3;
    BF4F(x0,x1,x2,x3,u0,u1,u2,u3);
    t4[A1(base)]     = u0;
    t4[A1(base+L)]   = cmulf(u1, Ws[tw]);
    t4[A1(base+2*L)] = cmulf(u2, Ws[2*tw]);
    t4[A1(base+3*L)] = cmulf(u3, Ws[3*tw]);
    __syncthreads();
  }
}

__device__ __forceinline__ void inv_r4_row(float2* t4, const float2* Ws, int tid){
  #pragma unroll
  for (int s = 0; s < 5; ++s){
    int H = 1 << (2*s);
    int j = tid & (H-1);
    int base = ((tid >> (2*s)) << (2*s+2)) + j;
    int tw = j << (8 - 2*s);
    float2 x0 = t4[A1(base)];
    float2 x1 = cmulf(t4[A1(base+H)],   conjf(Ws[tw]));
    float2 x2 = cmulf(t4[A1(base+2*H)], conjf(Ws[2*tw]));
    float2 x3 = cmulf(t4[A1(base+3*H)], conjf(Ws[3*tw]));
    float2 u0,u1,u2,u3;
    BF4I(x0,x1,x2,x3,u0,u1,u2,u3);
    t4[A1(base)] = u0;     t4[A1(base+H)] = u1;
    t4[A1(base+2*H)] = u2; t4[A1(base+3*H)] = u3;
    __syncthreads();
  }
}

// ---------------- precompute ----------------
__global__ void k_build_h(const float* __restrict__ h, float2* __restrict__ Z){
  int idx = blockIdx.x*256 + threadIdx.x; // NN
  int i = idx >> 10, j = idx & 1023;
  float v = 0.f;
  if (i >= 256 && i < 768 && j >= 256 && j < 768)
    v = h[(i-256)*512 + (j-256)];
  Z[idx] = make_float2(v, 0.f);
}

template<int DIR>
__global__ __launch_bounds__(256) void k_fft_row(float2* Z){
  __shared__ float2 bufA[N], bufB[N], Ws[512];
  int tid = threadIdx.x;
  size_t base = ((size_t)blockIdx.y * N + blockIdx.x) * N;
  genWs(Ws, 512, tid, 256);
  for (int k = tid; k < N; k += 256) bufA[k] = Z[base + k];
  __syncthreads();
  fft1024<DIR>(bufA, bufB, Ws, tid);
  for (int k = tid; k < N; k += 256) Z[base + k] = bufA[k];
}

__global__ void k_transpose_ip(float2* Z){
  __shared__ float2 ta[32][33], tb[32][33];
  int t = blockIdx.x, ti = 0;
  while (t >= 32 - ti){ t -= 32 - ti; ti++; }
  int tj = ti + t;
  size_t base = (size_t)blockIdx.y * NN;
  int ra = ti*32, ca = tj*32;
  for (int k = threadIdx.y; k < 32; k += 8){
    ta[k][threadIdx.x] = Z[base + (size_t)(ra+k)*N + ca + threadIdx.x];
    if (ti != tj)
      tb[k][threadIdx.x] = Z[base + (size_t)(ca+k)*N + ra + threadIdx.x];
  }
  __syncthreads();
  for (int k = threadIdx.y; k < 32; k += 8){
    Z[base + (size_t)(ra+k)*N + ca + threadIdx.x] = (ti!=tj) ? tb[threadIdx.x][k]
                                                             : ta[threadIdx.x][k];
    if (ti != tj)
      Z[base + (size_t)(ca+k)*N + ra + threadIdx.x] = ta[threadIdx.x][k];
  }
}

// ZT[idx] = fft2(pad h) at (k_j = idx>>10, k_i = idx&1023).
// Blocked 8-col colpass layout: HfCb[blk][p][c], k_i=rev4(p), k_j=unfold(blk*8+c).
__global__ void k_filters2(const float2* __restrict__ ZT, float2* __restrict__ HfCb){
  int id = blockIdx.x*256 + threadIdx.x; // NN
  int blk = id >> 13;
  int rem = id & 8191;
  int p = rem >> 3, c = rem & 7;
  int colp = (blk << 3) | c;
  int ki = rev4_10(p);
  int kj = unfoldc(colp);
  float2 v = ZT[((size_t)kj << 10) | (size_t)ki];
  float sgn = ((ki + kj) & 1) ? -1.f : 1.f;
  HfCb[id] = make_float2(sgn*v.x, sgn*v.y);
}

// ---------------- pA: fused G0+G1+K updates + s-build + radix-4 fwd row FFT --
// mode 0: normal. mode 1 (t==1): G0r treated as zero. mode 2 (t==0): all state
// zero, z = i*M0(y); writes K=0, G1=0 (buffer init), no G0/X/M reads.
__global__ __launch_bounds__(256) void k_pA(const float* __restrict__ X,
                                            const float* __restrict__ G0r,
                                            float* __restrict__ G0w,
                                            float* __restrict__ G1,
                                            float* __restrict__ K,
                                            const float* __restrict__ M,
                                            const float* __restrict__ y,
                                            float2* __restrict__ Zw,
                                            float2* __restrict__ Zd,
                                            int e0, int mode){
  __shared__ float2 t4[1088], Ws[768];
  __shared__ float g1row[1024];
  int tid = threadIdx.x;
  int bid = blockIdx.x;
  int i = ((bid & 7) << 7) + (bid >> 3);   // XCD row-chunk swizzle
  int ce = blockIdx.y, e = e0 + ce;
  size_t eb  = (size_t)e*NN;
  size_t rb  = eb + (size_t)i*N;
  size_t rbm = eb + (size_t)((i-1)&1023)*N;
  size_t rbp = eb + (size_t)((i+1)&1023)*N;
  float2* Zp = ZP(Zw, Zd, ce);
  size_t zb  = (size_t)i*N;
  genWs(Ws, 768, tid, 256);
  const float T = 1e4f;                    // TAU/MU2
  if (mode == 2){
    bool rcent = (i >= 256 && i < 768);
    for (int j = tid; j < N; j += 256){
      float m0 = 0.f;
      if (rcent && j >= 256 && j < 768)
        m0 = y[(size_t)e*262144 + (size_t)(i-256)*512 + (j-256)] * (MU1/(1.f + MU1));
      t4[A1(j)] = make_float2(0.f, m0);
      K[rb+j]  = 0.f;                      // state init (dual vars start at 0)
      G1[rb+j] = 0.f;
    }
  } else {
    // stage G1 row in LDS (breaks in-place write/read race across threads)
    for (int j = tid; j < N; j += 256) g1row[j] = G1[rb+j];
    __syncthreads();
    for (int j = tid; j < N; j += 256){
      float xm = X[rbm+j], x = X[rb+j], xp = X[rbp+j];
      float psi0  = xm - x;
      float psi0p = x - xp;                // psi0 at row i+1
      float g0  = (mode == 1) ? 0.f : G0r[rb+j];
      float g0p = (mode == 1) ? 0.f : G0r[rbp+j];
      float u0  = softf(2.f*psi0  - g0 *(1.f/MU2), T);
      float u0p = softf(2.f*psi0p - g0p*(1.f/MU2), T);
      float g0n  = MU2*(u0  - psi0 ) + g0;
      float g0np = MU2*(u0p - psi0p) + g0p;
      G0w[rb+j] = g0n;
      int jm = (j-1) & 1023, jp = (j+1) & 1023;
      // G1 (j-direction U-dual) update at j and j+1, from staged old values
      float xjm = X[rb+jm], xjp = X[rb+jp];   // L1 hits (same row)
      float psi1  = xjm - x;
      float psi1p = x - xjp;
      float g1  = g1row[j], g1p = g1row[jp];
      float u1  = softf(2.f*psi1  - g1 *(1.f/MU2), T);
      float u1p = softf(2.f*psi1p - g1p*(1.f/MU2), T);
      float g1n  = MU2*(u1  - psi1 ) + g1;
      float g1np = MU2*(u1p - psi1p) + g1p;
      G1[rb+j] = g1n;                      // in-place safe: reads were from LDS
      // K (W-dual) update, pointwise
      float kk = K[rb+j];
      float w  = fmaxf(2.f*x - kk*(1.f/MU3), 0.f);
      float kn = MU3*(w - x) + kk;
      K[rb+j] = kn;
      float s = kn + (g0np - g0n) + (g1np - g1n);
      t4[A1(j)] = make_float2(s, M[rb+j]);
    }
  }
  __syncthreads();
  fwd_r4_row(t4, Ws, tid);
  // storage order: Z[c] = F(unfoldc(c)); DIF left F(k) at pos rev4(k)
  for (int c = tid; c < N; c += 256)
    Zp[zb + c] = t4[A1(rev4_10(unfoldc(c)))];
}

// ---------------- fused column pass: radix-4 (2 stages/sync) + combine -------
#define TADDR(r,c) ((((r)*9) + (c)) ^ (((r) & 16) >> 1))
#define CPV 512
__global__ __launch_bounds__(CPV) void k_colpass(float2* __restrict__ Zw,
    float2* __restrict__ Zd, const float2* __restrict__ HfCb){
  __shared__ float2 tile[9216];
  __shared__ float2 Ws[768];
  int tid = threadIdx.x;
  int blk = blockIdx.x;              // 128 col-groups of 8
  float2* Zp = ZP(Zw, Zd, blockIdx.y);
  size_t zbase = (size_t)(blk<<3);
  genWs(Ws, 768, tid, CPV);
  for (int k = tid; k < 8192; k += CPV){
    int r = k >> 3, c = k & 7;
    tile[TADDR(r,c)] = Zp[zbase + (size_t)r*N + c];
  }
  __syncthreads();
  // forward stages 0+1
  {
    int c = tid & 7, j2 = tid >> 3;
    float2 v[4][4];
    #pragma unroll
    for (int a = 0; a < 4; ++a)
      #pragma unroll
      for (int b = 0; b < 4; ++b)
        v[a][b] = tile[TADDR(j2 + 64*b + 256*a, c)];
    #pragma unroll
    for (int b = 0; b < 4; ++b){
      int j1 = j2 + 64*b;
      float2 u0,u1,u2,u3;
      BF4F(v[0][b],v[1][b],v[2][b],v[3][b],u0,u1,u2,u3);
      v[0][b] = u0;
      v[1][b] = cmulf(u1, Ws[j1]);
      v[2][b] = cmulf(u2, Ws[2*j1]);
      v[3][b] = cmulf(u3, Ws[3*j1]);
    }
    int tw = j2 << 2;
    #pragma unroll
    for (int a = 0; a < 4; ++a){
      float2 u0,u1,u2,u3;
      BF4F(v[a][0],v[a][1],v[a][2],v[a][3],u0,u1,u2,u3);
      tile[TADDR(j2 + 256*a, c)]       = u0;
      tile[TADDR(j2 + 64 + 256*a, c)]  = cmulf(u1, Ws[tw]);
      tile[TADDR(j2 + 128 + 256*a, c)] = cmulf(u2, Ws[2*tw]);
      tile[TADDR(j2 + 192 + 256*a, c)] = cmulf(u3, Ws[3*tw]);
    }
  }
  __syncthreads();
  // forward stages 2+3
  {
    int c = tid & 7, vv = tid >> 3;
    int B2 = vv >> 2, j2 = vv & 3;
    int r0 = 64*B2 + j2;
    float2 v[4][4];
    #pragma unroll
    for (int a = 0; a < 4; ++a)
      #pragma unroll
      for (int b = 0; b < 4; ++b)
        v[a][b] = tile[TADDR(r0 + 4*b + 16*a, c)];
    #pragma unroll
    for (int b = 0; b < 4; ++b){
      int tw = (j2 + 4*b) << 4;
      float2 u0,u1,u2,u3;
      BF4F(v[0][b],v[1][b],v[2][b],v[3][b],u0,u1,u2,u3);
      v[0][b] = u0;
      v[1][b] = cmulf(u1, Ws[tw]);
      v[2][b] = cmulf(u2, Ws[2*tw]);
      v[3][b] = cmulf(u3, Ws[3*tw]);
    }
    int tw3 = j2 << 6;
    #pragma unroll
    for (int a = 0; a < 4; ++a){
      float2 u0,u1,u2,u3;
      BF4F(v[a][0],v[a][1],v[a][2],v[a][3],u0,u1,u2,u3);
      tile[TADDR(r0 + 16*a, c)]      = u0;
      tile[TADDR(r0 + 16*a + 4, c)]  = cmulf(u1, Ws[tw3]);
      tile[TADDR(r0 + 16*a + 8, c)]  = cmulf(u2, Ws[2*tw3]);
      tile[TADDR(r0 + 16*a + 12, c)] = cmulf(u3, Ws[3*tw3]);
    }
  }
  __syncthreads();
  // prefetch combine's filter values (even columns only; blk!=0 path),
  // one barrier before use -> short register lifetime, latency hidden by fwd4
  float2 hfpre[8];
  size_t fbase = (size_t)blk << 13;
  if (blk != 0){
    #pragma unroll
    for (int u = 0; u < 8; ++u){
      int k2 = tid + u*CPV;
      int idx = ((k2 >> 2) << 3) | ((k2 & 3) << 1);
      hfpre[u] = HfCb[fbase + idx];
    }
  }
  // forward stage 4
  for (int k = tid; k < 2048; k += CPV){
    int c = k & 7, t = k >> 3;
    int r = 4*t;
    float2 x0 = tile[TADDR(r,c)],   x1 = tile[TADDR(r+1,c)];
    float2 x2 = tile[TADDR(r+2,c)], x3 = tile[TADDR(r+3,c)];
    float2 u0,u1,u2,u3;
    BF4F(x0,x1,x2,x3,u0,u1,u2,u3);
    tile[TADDR(r,c)] = u0; tile[TADDR(r+1,c)] = u1;
    tile[TADDR(r+2,c)] = u2; tile[TADDR(r+3,c)] = u3;
  }
  __syncthreads();
  // spectral combine on Hermitian pairs; Rdiv computed in-kernel
  if (blk != 0){
    #pragma unroll
    for (int u = 0; u < 8; ++u){
      int k2 = tid + u*CPV;
      int p = k2 >> 2;
      int c = (k2 & 3) << 1;
      int k1 = rev4_10(p);
      int q = rev4_10((1024 - k1) & 1023);
      int colp = (blk << 3) + c;
      float2 Zk = tile[TADDR(p,c)];
      float2 Zr = tile[TADDR(q,c^1)];
      float Sre = 0.5f*(Zk.x + Zr.x);
      float Sim = 0.5f*(Zk.y - Zr.y);
      float Mre = 0.5f*(Zk.y + Zr.y);
      float Mim = 0.5f*(Zr.x - Zk.x);
      float2 hf = hfpre[u];
      int kj = unfoldc(colp);
      float cA = Ws[(k1 < 768) ? k1 : 1024 - k1].x;
      float cB = Ws[(kj < 768) ? kj : 1024 - kj].x;
      float ltl = 4.f - 2.f*cA - 2.f*cB;
      float mag2 = hf.x*hf.x + hf.y*hf.y;
      float rd = 9.5367431640625e-7f / (MU1*mag2 + MU2*ltl + MU3); // 1/N^2 folded
      float fr = rd*(Sre + hf.x*Mre + hf.y*Mim);
      float fi = rd*(Sim + hf.x*Mim - hf.y*Mre);
      float hr = hf.x*fr - hf.y*fi;
      float hi = hf.x*fi + hf.y*fr;
      tile[TADDR(p,c)]   = make_float2(fr - hi, fi + hr);
      tile[TADDR(q,c^1)] = make_float2(fr + hi, hr - fi);
    }
  } else {
    for (int k = tid; k < 8192; k += CPV){
      int p = k >> 3, c = k & 7;
      int k1 = rev4_10(p);
      int q = rev4_10((1024 - k1) & 1023);
      int colp = (blk << 3) + c;
      int cm = (colp < 2) ? c : (c ^ 1);
      int pid = (q << 3) | cm;
      if (pid < k) continue;
      float2 Zk = tile[TADDR(p,c)];
      float2 Zr = tile[TADDR(q,cm)];
      float Sre = 0.5f*(Zk.x + Zr.x);
      float Sim = 0.5f*(Zk.y - Zr.y);
      float Mre = 0.5f*(Zk.y + Zr.y);
      float Mim = 0.5f*(Zr.x - Zk.x);
      float2 hf = HfCb[fbase + k];
      int kj = unfoldc(colp);
      float cA = Ws[(k1 < 768) ? k1 : 1024 - k1].x;
      float cB = Ws[(kj < 768) ? kj : 1024 - kj].x;
      float ltl = 4.f - 2.f*cA - 2.f*cB;
      float mag2 = hf.x*hf.x + hf.y*hf.y;
      float rd = 9.5367431640625e-7f / (MU1*mag2 + MU2*ltl + MU3);
      float fr = rd*(Sre + hf.x*Mre + hf.y*Mim);
      float fi = rd*(Sim + hf.x*Mim - hf.y*Mre);
      float hr = hf.x*fr - hf.y*fi;
      float hi = hf.x*fi + hf.y*fr;
      tile[TADDR(p,c)] = make_float2(fr - hi, fi + hr);
      if (pid != k) tile[TADDR(q,cm)] = make_float2(fr + hi, hr - fi);
    }
  }
  __syncthreads();
  // inverse stages 0+1
  {
    int c = tid & 7, G = tid >> 3;
    int r0 = 16*G;
    float2 v[4][4];
    #pragma unroll
    for (int a = 0; a < 4; ++a)
      #pragma unroll
      for (int b = 0; b < 4; ++b)
        v[a][b] = tile[TADDR(r0 + 4*a + b, c)];
    #pragma unroll
    for (int a = 0; a < 4; ++a){
      float2 u0,u1,u2,u3;
      BF4I(v[a][0],v[a][1],v[a][2],v[a][3],u0,u1,u2,u3);
      v[a][0]=u0; v[a][1]=u1; v[a][2]=u2; v[a][3]=u3;
    }
    #pragma unroll
    for (int b = 0; b < 4; ++b){
      int tw = b << 6;
      float2 x0 = v[0][b];
      float2 x1 = cmulf(v[1][b], conjf(Ws[tw]));
      float2 x2 = cmulf(v[2][b], conjf(Ws[2*tw]));
      float2 x3 = cmulf(v[3][b], conjf(Ws[3*tw]));
      float2 u0,u1,u2,u3;
      BF4I(x0,x1,x2,x3,u0,u1,u2,u3);
      tile[TADDR(r0 + b, c)]      = u0;
      tile[TADDR(r0 + 4 + b, c)]  = u1;
      tile[TADDR(r0 + 8 + b, c)]  = u2;
      tile[TADDR(r0 + 12 + b, c)] = u3;
    }
  }
  __syncthreads();
  // inverse stages 2+3
  {
    int c = tid & 7, vv = tid >> 3;
    int T3 = vv >> 4, jj = vv & 15;
    int r0 = 256*T3 + jj;
    float2 v[4][4];
    #pragma unroll
    for (int a = 0; a < 4; ++a)
      #pragma unroll
      for (int b = 0; b < 4; ++b)
        v[a][b] = tile[TADDR(r0 + 16*a + 64*b, c)];
    int tw2 = jj << 4;
    #pragma unroll
    for (int b = 0; b < 4; ++b){
      float2 x0 = v[0][b];
      float2 x1 = cmulf(v[1][b], conjf(Ws[tw2]));
      float2 x2 = cmulf(v[2][b], conjf(Ws[2*tw2]));
      float2 x3 = cmulf(v[3][b], conjf(Ws[3*tw2]));
      float2 u0,u1,u2,u3;
      BF4I(x0,x1,x2,x3,u0,u1,u2,u3);
      v[0][b]=u0; v[1][b]=u1; v[2][b]=u2; v[3][b]=u3;
    }
    #pragma unroll
    for (int a = 0; a < 4; ++a){
      int tw = (jj + 16*a) << 2;
      float2 x0 = v[a][0];
      float2 x1 = cmulf(v[a][1], conjf(Ws[tw]));
      float2 x2 = cmulf(v[a][2], conjf(Ws[2*tw]));
      float2 x3 = cmulf(v[a][3], conjf(Ws[3*tw]));
      float2 u0,u1,u2,u3;
      BF4I(x0,x1,x2,x3,u0,u1,u2,u3);
      tile[TADDR(r0 + 16*a, c)]       = u0;
      tile[TADDR(r0 + 16*a + 64, c)]  = u1;
      tile[TADDR(r0 + 16*a + 128, c)] = u2;
      tile[TADDR(r0 + 16*a + 192, c)] = u3;
    }
  }
  __syncthreads();
  // inverse stage 4
  for (int k = tid; k < 2048; k += CPV){
    int c = k & 7, t = k >> 3;
    float2 x0 = tile[TADDR(t,c)];
    float2 x1 = cmulf(tile[TADDR(t+256,c)], conjf(Ws[t]));
    float2 x2 = cmulf(tile[TADDR(t+512,c)], conjf(Ws[2*t]));
    float2 x3 = cmulf(tile[TADDR(t+768,c)], conjf(Ws[3*t]));
    float2 u0,u1,u2,u3;
    BF4I(x0,x1,x2,x3,u0,u1,u2,u3);
    tile[TADDR(t,c)] = u0;     tile[TADDR(t+256,c)] = u1;
    tile[TADDR(t+512,c)] = u2; tile[TADDR(t+768,c)] = u3;
  }
  __syncthreads();
  for (int k = tid; k < 8192; k += CPV){
    int r = k >> 3, c = k & 7;
    Zp[zbase + (size_t)r*N + c] = tile[TADDR(r,c)];
  }
}

// ---------------- p5: radix-4 inverse row FFT; X,M updates; crop out ---------
__global__ __launch_bounds__(256) void k_p5(float2* __restrict__ Zw,
                                            float2* __restrict__ Zd,
                                            float* __restrict__ X,
                                            float* __restrict__ M,
                                            const float* __restrict__ y,
                                            float* __restrict__ out, int writeOut,
                                            int e0, int first){
  __shared__ float2 t4[1088], Ws[768];
  int tid = threadIdx.x;
  int i = blockIdx.x, ce = blockIdx.y, e = e0 + ce;
  float2* Zp = ZP(Zw, Zd, ce);
  size_t zb = (size_t)i*N;
  size_t sb = (size_t)e*NN + (size_t)i*N;
  genWs(Ws, 768, tid, 256);
  // fused global load + fold/digit-reversal scatter (no staging buffer)
  for (int c = tid; c < N; c += 256)
    t4[A1(rev4_10(unfoldc(c)))] = Zp[zb + c];
  __syncthreads();
  inv_r4_row(t4, Ws, tid);
  bool rcent = (i >= 256 && i < 768);
  for (int j = tid; j < N; j += 256){
    float2 xv = t4[A1(j)];
    float x = xv.x, hx = xv.y;
    X[sb+j] = x;
    bool cent = rcent && (j >= 256 && j < 768);
    float cty  = cent ? y[(size_t)e*262144 + (size_t)(i-256)*512 + (j-256)] : 0.f;
    float m = first ? (cent ? cty*(MU1/(1.f+MU1)) : 0.f) : M[sb+j];
    float vdiv = cent ? (1.f/(1.f + MU1)) : (1.f/MU1);
    float v = vdiv*(2.f*MU1*hx - m + cty);
    M[sb+j] = MU1*(v - hx) + m;
    if (writeOut && cent)
      out[(size_t)e*262144 + (size_t)(i-256)*512 + (j-256)] = x;
  }
}

__global__ void k_crop(const float* __restrict__ X, float* __restrict__ out){
  int t = blockIdx.x*256 + threadIdx.x; // 8*512*512
  int e = t >> 18;
  int r = (t >> 9) & 511;
  int c = t & 511;
  out[t] = X[(size_t)e*NN + (size_t)(r+256)*N + (c+256)];
}

extern "C" void kernel_launch(void* const* d_in, const int* in_sizes, int n_in,
                              void* d_out, int out_size, void* d_ws, size_t ws_size,
                              hipStream_t stream){
  const float* y = (const float*)d_in[0];   // (8,1,512,512)
  const float* h = (const float*)d_in[1];   // (512,512)
  float* out = (float*)d_out;

  size_t fplane = (size_t)BATCH * NN;
  float* X   = (float*)d_ws;
  float* G1  = X   + fplane;
  float* K   = G1  + fplane;
  float* M   = K   + fplane;
  float* G0a = M   + fplane;
  float* G0b = G0a + fplane;
  float2* HfCb = (float2*)(G0b + fplane);
  float2* Zw   = HfCb + NN;
  size_t used = (size_t)((char*)Zw - (char*)d_ws);
  size_t zcap = (ws_size > used) ? (ws_size - used) / ((size_t)NN * sizeof(float2)) : 0;

  int CH; float2* Zd; bool needCrop;
  if (zcap >= 8){       CH = 8; Zd = Zw + 7*(size_t)NN; needCrop = true; }
  else if (zcap == 7){  CH = 8; Zd = (float2*)d_out;    needCrop = true; }
  else if (zcap >= 4){  CH = 4; Zd = Zw; needCrop = false; }
  else if (zcap >= 2){  CH = 2; Zd = Zw; needCrop = false; }
  else if (zcap >= 1){  CH = 1; Zd = Zw; needCrop = false; }
  else {                CH = 1; Zw = (float2*)d_out; Zd = Zw; needCrop = true; }

  // precompute: fft2(pad h) in Zw plane 0, filters in blocked layout
  k_build_h<<<NN/256, 256, 0, stream>>>(h, Zw);
  k_fft_row<-1><<<dim3(N,1), 256, 0, stream>>>(Zw);
  k_transpose_ip<<<dim3(528,1), dim3(32,8), 0, stream>>>(Zw);
  k_fft_row<-1><<<dim3(N,1), 256, 0, stream>>>(Zw);
  k_filters2<<<NN/256, 256, 0, stream>>>(Zw, HfCb);

  for (int t = 0; t < 20; ++t){
    const float* G0r = (t & 1) ? G0b : G0a;
    float*       G0w = (t & 1) ? G0a : G0b;
    int mode = (t == 0) ? 2 : ((t == 1) ? 1 : 0);
    int wo = (t == 19 && !needCrop) ? 1 : 0;
    for (int e0 = 0; e0 < BATCH; e0 += CH){
      k_pA<<<dim3(N,CH), 256, 0, stream>>>(X, G0r, G0w, G1, K, M, y, Zw, Zd, e0, mode);
      k_colpass<<<dim3(128,CH), CPV, 0, stream>>>(Zw, Zd, HfCb);
      k_p5<<<dim3(N,CH), 256, 0, stream>>>(Zw, Zd, X, M, y, out, wo, e0, (t==0)?1:0);
    }
  }
  if (needCrop)
    k_crop<<<(BATCH*512*512)/256, 256, 0, stream>>>(X, out);
}